// Round 7
// baseline (504.056 us; speedup 1.0000x reference)
//
#include <hip/hip_runtime.h>

typedef short v8s __attribute__((ext_vector_type(8)));
typedef float v4f __attribute__((ext_vector_type(4)));
using u16 = unsigned short;

// ============================================================================
// TILED LAYOUTS (all bf16). Every hot GLOBAL LOAD is base + lane*16B (1KB,
// fully coalesced) -- confirmed r3: attn 134->94.7us from addressing alone.
// r4: q-tile height = K/V reuse (32-row tiles doubled traffic, cancelled TLP).
// r5: raw-barrier null; XCD affinity cuts FETCH 3.4x but not time.
// r6: 2 waves/SIMD same-block = +8% only -> barrier lockstep means phases SUM.
// r7: KEY-SPLIT: 2 independent blocks/CU (own barriers -> phases overlap
//     across blocks) at CONSTANT traffic (same 64-row q tile, half the keys).
//     Halves write own-normalized bf16 O to o0/o1 (reused buffers, no new ws);
//     gemm_proj recombines A = (L0*o0 + L1*o1)/(L0+L1) per row.
//
// TILE16 (activations/out, M x 256): fragment tile = 16 rows x 256 ch.
//   idx(row,ch) = ((row>>4)*8 + (ch>>5))*512 + (((ch>>3)&3)*16 + (row&15))*8 + (ch&7)
// WTILE (weights, 256x256):
//   idx(k,n) = ((n>>4)*8 + (k>>5))*512 + (((k>>3)&3)*16 + (n&15))*8 + (k&7)
// VTILE (V^T, per batch): tile(chunk64, chblk, ks32) as B-operand of PV.
//
// QSCALE = log2(e)/16 folded into Wq/bq so attn does exp2f(sc) directly.
// ============================================================================
#define QSCALE 0.09016844f

__device__ __forceinline__ u16 f2b(float f) {
  union { float f; unsigned u; } v; v.f = f;
  unsigned r = v.u + 0x7FFFu + ((v.u >> 16) & 1u);
  return (u16)(r >> 16);
}
__device__ __forceinline__ float b2f(u16 h) {
  union { unsigned u; float f; } v; v.u = ((unsigned)h) << 16;
  return v.f;
}

// ---------------- LayerNorm + bf16 casts (tiled outputs) ----------------
__global__ void ln_prep(const float* __restrict__ x, const float* __restrict__ ctx,
                        const float* __restrict__ gamma, const float* __restrict__ beta,
                        float* __restrict__ xn_f, u16* __restrict__ xn_b,
                        u16* __restrict__ ctx_b)
{
  const int tid = threadIdx.x;
  const int wid = tid >> 6, lane = tid & 63;
  const int row = blockIdx.x * 4 + wid;
  const size_t tidx = ((size_t)(row >> 4) * 8 + (lane >> 3)) * 512 +
                      (((lane >> 1) & 3) * 16 + (row & 15)) * 8 + (lane & 1) * 4;
  if (blockIdx.y == 0) {
    const float4 xv = *(const float4*)(x + (size_t)row * 256 + lane * 4);
    float s1 = xv.x + xv.y + xv.z + xv.w;
    float s2 = xv.x*xv.x + xv.y*xv.y + xv.z*xv.z + xv.w*xv.w;
#pragma unroll
    for (int m = 32; m >= 1; m >>= 1) {
      s1 += __shfl_xor(s1, m);
      s2 += __shfl_xor(s2, m);
    }
    const float mu  = s1 * (1.0f/256.0f);
    const float var = s2 * (1.0f/256.0f) - mu*mu;
    const float rs  = rsqrtf(var + 1e-3f);
    const float4 g = *(const float4*)(gamma + lane*4);
    const float4 b = *(const float4*)(beta  + lane*4);
    float4 y;
    y.x = (xv.x-mu)*rs*g.x + b.x;
    y.y = (xv.y-mu)*rs*g.y + b.y;
    y.z = (xv.z-mu)*rs*g.z + b.z;
    y.w = (xv.w-mu)*rs*g.w + b.w;
    *(float4*)(xn_f + (size_t)row*256 + lane*4) = y;
    ushort4 yb; yb.x=f2b(y.x); yb.y=f2b(y.y); yb.z=f2b(y.z); yb.w=f2b(y.w);
    *(ushort4*)(xn_b + tidx) = yb;
  } else {
    const float4 cv = *(const float4*)(ctx + (size_t)row * 256 + lane * 4);
    ushort4 cb; cb.x=f2b(cv.x); cb.y=f2b(cv.y); cb.z=f2b(cv.z); cb.w=f2b(cv.w);
    *(ushort4*)(ctx_b + tidx) = cb;
  }
}

// ---------------- weight transpose + bf16 cast into WTILE ----------------
__global__ void wtrans(const float* __restrict__ wq, const float* __restrict__ wk,
                       const float* __restrict__ wv, const float* __restrict__ wp,
                       u16* __restrict__ tq, u16* __restrict__ tk,
                       u16* __restrict__ tv, u16* __restrict__ tp)
{
  const float* src; u16* dst; float scl = 1.0f;
  switch (blockIdx.y) {
    case 0:  src = wq; dst = tq; scl = QSCALE; break;
    case 1:  src = wk; dst = tk; break;
    case 2:  src = wv; dst = tv; break;
    default: src = wp; dst = tp; break;
  }
  const int t  = threadIdx.x;
  const int kk = blockIdx.x * 16 + (t >> 4);
  const int n0 = (t & 15) * 16;
  const size_t base = (size_t)((t & 15) * 8 + (kk >> 5)) * 512 +
                      ((kk >> 3) & 3) * 16 * 8 + (kk & 7);
#pragma unroll
  for (int j = 0; j < 16; j++)
    dst[base + (size_t)j * 8] = f2b(src[(size_t)kk * 256 + n0 + j] * scl);
}

// ---------------- q/k/v GEMM (r4 version, proven) ----------------
__global__ __launch_bounds__(256) void gemm_qkv(
    const u16* __restrict__ xn_b, const u16* __restrict__ ctx_b,
    const u16* __restrict__ wqt, const u16* __restrict__ wkt, const u16* __restrict__ wvt,
    const float* __restrict__ bq, const float* __restrict__ bk, const float* __restrict__ bv,
    u16* __restrict__ qo, u16* __restrict__ ko, u16* __restrict__ vto)
{
  const int mode = blockIdx.y;
  const u16* A; const u16* Wt; const float* bias;
  if (mode == 0)      { A = xn_b;  Wt = wqt; bias = bq; }
  else if (mode == 1) { A = ctx_b; Wt = wkt; bias = bk; }
  else                { A = ctx_b; Wt = wvt; bias = bv; }
  const float bscale = (mode == 0) ? QSCALE : 1.0f;
  const int wid = threadIdx.x >> 6, lane = threadIdx.x & 63;
  const int lm = lane & 15, q4 = lane >> 4;
  const int m0 = blockIdx.x * 64 + wid * 16;
  const u16* abase = A + (size_t)(m0 >> 4) * 4096 + lane * 8;
  v8s af[8];
#pragma unroll
  for (int kf = 0; kf < 8; kf++) af[kf] = *(const v8s*)(abase + kf * 512);
#pragma unroll
  for (int ct = 0; ct < 16; ct++) {
    const int c = ct * 16 + lm;
    const u16* wbase = Wt + (size_t)ct * 4096 + lane * 8;
    v8s wf[8];
#pragma unroll
    for (int kf = 0; kf < 8; kf++) wf[kf] = *(const v8s*)(wbase + kf * 512);
    v4f a0 = {0.f,0.f,0.f,0.f}, a1 = a0, a2 = a0, a3 = a0;
    a0 = __builtin_amdgcn_mfma_f32_16x16x32_bf16(af[0], wf[0], a0, 0, 0, 0);
    a1 = __builtin_amdgcn_mfma_f32_16x16x32_bf16(af[2], wf[2], a1, 0, 0, 0);
    a2 = __builtin_amdgcn_mfma_f32_16x16x32_bf16(af[4], wf[4], a2, 0, 0, 0);
    a3 = __builtin_amdgcn_mfma_f32_16x16x32_bf16(af[6], wf[6], a3, 0, 0, 0);
    a0 = __builtin_amdgcn_mfma_f32_16x16x32_bf16(af[1], wf[1], a0, 0, 0, 0);
    a1 = __builtin_amdgcn_mfma_f32_16x16x32_bf16(af[3], wf[3], a1, 0, 0, 0);
    a2 = __builtin_amdgcn_mfma_f32_16x16x32_bf16(af[5], wf[5], a2, 0, 0, 0);
    a3 = __builtin_amdgcn_mfma_f32_16x16x32_bf16(af[7], wf[7], a3, 0, 0, 0);
    const v4f acc = (a0 + a1) + (a2 + a3);
    const float bb = bias[c] * bscale;
    if (mode == 2) {
      const int b = m0 >> 12;
      const int chunk = (m0 & 4095) >> 6;
      const int kic = (m0 & 63) + q4 * 4;
      const int ks = kic >> 5;
      const int q4p = (kic >> 3) & 3;
      const size_t idx = ((size_t)(b * 64 + chunk) * 32 + (c >> 4) * 2 + ks) * 512 +
                         (q4p * 16 + (c & 15)) * 8 + (q4 & 1) * 4;
      ushort4 pk;
      pk.x = f2b(acc[0] + bb); pk.y = f2b(acc[1] + bb);
      pk.z = f2b(acc[2] + bb); pk.w = f2b(acc[3] + bb);
      *(ushort4*)(vto + idx) = pk;
    } else {
      u16* out = (mode == 0) ? qo : ko;
      const size_t base = ((size_t)(m0 >> 4) * 8 + (c >> 5)) * 512 +
                          (((c >> 3) & 3) * 16 + q4 * 4) * 8 + (c & 7);
#pragma unroll
      for (int r = 0; r < 4; r++)
        out[base + (size_t)r * 8] = f2b(acc[r] + bb);
    }
  }
}

// ---------------- flash-style attention, v10: key-split ----------------
// = v9 body (8 waves, 64-row Q tile, 128-key chunks, coalesced tiled loads)
// over HALF the keys per block. Grid 512 -> 2 independent blocks/CU with
// independent barriers: phase overlap across blocks at constant total traffic.
// bid decode: batch = (bid&7)>>1 (XCD affinity), ks = bid&1, qblk = bid>>3.
// Each half normalizes O by its own L and writes bf16 to o0/o1; partial row
// sums go to Lq[ks]. gemm_proj recombines.
__global__ __launch_bounds__(512, 4) void attn_kernel(
    const u16* __restrict__ q, const u16* __restrict__ k,
    const u16* __restrict__ vt, u16* __restrict__ o0, u16* __restrict__ o1,
    float* __restrict__ Lq)
{
  __shared__ u16 P[2][64][136];   // [buf][q][key128 +8 pad] bf16, 34.8 KB
  __shared__ float Lp[8][64];
  __shared__ float Lt[64];
  const int bid  = blockIdx.x;
  const int b    = (bid & 7) >> 1;   // batch -> XCD pair
  const int ks   = bid & 1;          // key half
  const int qblk = bid >> 3;         // [0,64)
  const int tid  = threadIdx.x;
  const int w    = tid >> 6, lane = tid & 63;  // w in [0,8)
  const int lm   = lane & 15, q4 = lane >> 4;
  const int m0   = qblk * 64;
  const u16* qb = q  + (size_t)b * 1048576;
  const u16* kb = k  + (size_t)b * 1048576;
  const u16* vb = vt + (size_t)b * 1048576;
  const int c0 = ks * 16;            // first 128-key chunk of this half

  // Q fragments for 4 q-tiles (coalesced 1KB loads), held all kernel
  v8s qf[4][8];
#pragma unroll
  for (int qt = 0; qt < 4; qt++) {
    const u16* qbase = qb + (size_t)((m0 >> 4) + qt) * 4096 + lane * 8;
#pragma unroll
    for (int kf = 0; kf < 8; kf++) qf[qt][kf] = *(const v8s*)(qbase + kf * 512);
  }

  v4f o[4][2];   // [qt][ct]: this wave's 32 channels
#pragma unroll
  for (int qt = 0; qt < 4; qt++)
#pragma unroll
    for (int ct = 0; ct < 2; ct++) o[qt][ct] = (v4f){0.f, 0.f, 0.f, 0.f};
  float lsum[4] = {0.f, 0.f, 0.f, 0.f};

  // K fragments for first chunk: strip = c0*8 + w
  v8s kfr[8];
  {
    const u16* kbase = kb + (size_t)(c0 * 8 + w) * 4096 + lane * 8;
#pragma unroll
    for (int kf = 0; kf < 8; kf++) kfr[kf] = *(const v8s*)(kbase + kf * 512);
  }

  for (int c128 = c0; c128 < c0 + 16; c128++) {
    const int pb = c128 & 1;
    // V loads for this chunk (this wave's 2 ch-blocks x 4 key-slices)
    v8s vfr[2][4];
#pragma unroll
    for (int ct = 0; ct < 2; ct++)
#pragma unroll
      for (int j = 0; j < 4; j++) {
        const size_t tile = (size_t)(c128 * 2 + (j >> 1)) * 32 +
                            (w * 2 + ct) * 2 + (j & 1);
        vfr[ct][j] = *(const v8s*)(vb + tile * 512 + lane * 8);
      }
    // phase A: S^T strip via mfma(K, Q)
    v4f sc[4];
#pragma unroll
    for (int qt = 0; qt < 4; qt++) sc[qt] = (v4f){0.f, 0.f, 0.f, 0.f};
#pragma unroll
    for (int kf = 0; kf < 8; kf++)
#pragma unroll
      for (int qt = 0; qt < 4; qt++)
        sc[qt] = __builtin_amdgcn_mfma_f32_16x16x32_bf16(kfr[kf], qf[qt][kf], sc[qt], 0, 0, 0);
    // K prefetch for next chunk (wrap within this half)
    {
      const int nc = c0 + ((c128 + 1 - c0) & 15);
      const u16* kbase = kb + (size_t)(nc * 8 + w) * 4096 + lane * 8;
#pragma unroll
      for (int kf = 0; kf < 8; kf++) kfr[kf] = *(const v8s*)(kbase + kf * 512);
    }
    // exp2 (scale pre-folded into q) -> packed bf16 -> one b64 write per q-tile
#pragma unroll
    for (int qt = 0; qt < 4; qt++) {
      const float e0 = exp2f(sc[qt][0]);
      const float e1 = exp2f(sc[qt][1]);
      const float e2 = exp2f(sc[qt][2]);
      const float e3 = exp2f(sc[qt][3]);
      lsum[qt] += (e0 + e1) + (e2 + e3);
      unsigned d0, d1;
      asm("v_cvt_pk_bf16_f32 %0, %1, %2" : "=v"(d0) : "v"(e0), "v"(e1));
      asm("v_cvt_pk_bf16_f32 %0, %1, %2" : "=v"(d1) : "v"(e2), "v"(e3));
      uint2 pk; pk.x = d0; pk.y = d1;
      *(uint2*)(&P[pb][qt * 16 + lm][w * 16 + q4 * 4]) = pk;
    }
    __syncthreads();
    // phase B: O[64q x 32ch(w)] += P * V over 4 key-slices
#pragma unroll
    for (int qt = 0; qt < 4; qt++) {
      v8s pf[4];
#pragma unroll
      for (int j = 0; j < 4; j++)
        pf[j] = *(const v8s*)(&P[pb][qt * 16 + lm][j * 32 + q4 * 8]);
#pragma unroll
      for (int ct = 0; ct < 2; ct++)
#pragma unroll
        for (int j = 0; j < 4; j++)
          o[qt][ct] = __builtin_amdgcn_mfma_f32_16x16x32_bf16(pf[j], vfr[ct][j], o[qt][ct], 0, 0, 0);
    }
  }

  // partial l reduce: across q4 groups, then across the 8 waves
#pragma unroll
  for (int qt = 0; qt < 4; qt++) {
    float t = lsum[qt];
    t += __shfl_xor(t, 16);
    t += __shfl_xor(t, 32);
    lsum[qt] = t;
  }
  if (q4 == 0) {
#pragma unroll
    for (int qt = 0; qt < 4; qt++) Lp[w][qt * 16 + lm] = lsum[qt];
  }
  __syncthreads();
  if (tid < 64) {
    float t = 0.f;
#pragma unroll
    for (int ww = 0; ww < 8; ww++) t += Lp[ww][tid];
    Lt[tid] = t;
    Lq[ks * 16384 + b * 4096 + m0 + tid] = t;   // partial row-sum for combine
  }
  __syncthreads();

  // own-normalized partial O -> o0/o1 (TILE16 bf16)
  u16* od = ks ? o1 : o0;
  const int rstrip0 = (b * 4096 + m0) >> 4;
#pragma unroll
  for (int qt = 0; qt < 4; qt++)
#pragma unroll
    for (int r = 0; r < 4; r++) {
      const float linv = 1.0f / Lt[qt * 16 + q4 * 4 + r];
#pragma unroll
      for (int ct = 0; ct < 2; ct++) {
        const int ch = w * 32 + ct * 16 + lm;
        const size_t idx = ((size_t)(rstrip0 + qt) * 8 + (ch >> 5)) * 512 +
                           (((ch >> 3) & 3) * 16 + q4 * 4 + r) * 8 + (ch & 7);
        od[idx] = f2b(o[qt][ct][r] * linv);
      }
    }
}

// ---------------- proj GEMM + key-half combine + bias + residual ------------
// A = (L0*o0 + L1*o1)/(L0+L1) per row, rebuilt in registers during A-frag load.
__global__ __launch_bounds__(256) void gemm_proj(
    const u16* __restrict__ o0, const u16* __restrict__ o1,
    const float* __restrict__ Lq,
    const u16* __restrict__ Wt, const float* __restrict__ bias,
    const float* __restrict__ xn_f, float* __restrict__ out)
{
  const int wid = threadIdx.x >> 6, lane = threadIdx.x & 63;
  const int lm = lane & 15, q4 = lane >> 4;
  const int m0 = blockIdx.x * 64 + wid * 16;
  // per-lane row weights (row = m0 + lm for A-fragments)
  const float l0 = Lq[m0 + lm];
  const float l1 = Lq[16384 + m0 + lm];
  const float w0 = l0 / (l0 + l1);
  const float w1 = 1.0f - w0;
  const u16* a0base = o0 + (size_t)(m0 >> 4) * 4096 + lane * 8;
  const u16* a1base = o1 + (size_t)(m0 >> 4) * 4096 + lane * 8;
  v8s af[8];
#pragma unroll
  for (int kf = 0; kf < 8; kf++) {
    const v8s x0 = *(const v8s*)(a0base + kf * 512);
    const v8s x1 = *(const v8s*)(a1base + kf * 512);
    v8s m;
#pragma unroll
    for (int e = 0; e < 8; e++) {
      const float f = w0 * b2f((u16)x0[e]) + w1 * b2f((u16)x1[e]);
      m[e] = (short)f2b(f);
    }
    af[kf] = m;
  }
#pragma unroll
  for (int ct = 0; ct < 16; ct++) {
    const int c = ct * 16 + lm;
    const u16* wbase = Wt + (size_t)ct * 4096 + lane * 8;
    v8s wf[8];
#pragma unroll
    for (int kf = 0; kf < 8; kf++) wf[kf] = *(const v8s*)(wbase + kf * 512);
    v4f a0 = {0.f,0.f,0.f,0.f}, a1 = a0, a2 = a0, a3 = a0;
    a0 = __builtin_amdgcn_mfma_f32_16x16x32_bf16(af[0], wf[0], a0, 0, 0, 0);
    a1 = __builtin_amdgcn_mfma_f32_16x16x32_bf16(af[2], wf[2], a1, 0, 0, 0);
    a2 = __builtin_amdgcn_mfma_f32_16x16x32_bf16(af[4], wf[4], a2, 0, 0, 0);
    a3 = __builtin_amdgcn_mfma_f32_16x16x32_bf16(af[6], wf[6], a3, 0, 0, 0);
    a0 = __builtin_amdgcn_mfma_f32_16x16x32_bf16(af[1], wf[1], a0, 0, 0, 0);
    a1 = __builtin_amdgcn_mfma_f32_16x16x32_bf16(af[3], wf[3], a1, 0, 0, 0);
    a2 = __builtin_amdgcn_mfma_f32_16x16x32_bf16(af[5], wf[5], a2, 0, 0, 0);
    a3 = __builtin_amdgcn_mfma_f32_16x16x32_bf16(af[7], wf[7], a3, 0, 0, 0);
    const v4f acc = (a0 + a1) + (a2 + a3);
    const float bb = bias[c];
#pragma unroll
    for (int r = 0; r < 4; r++) {
      const size_t idx = (size_t)(m0 + q4 * 4 + r) * 256 + c;
      out[idx] = xn_f[idx] + acc[r] + bb;
    }
  }
}

extern "C" void kernel_launch(void* const* d_in, const int* in_sizes, int n_in,
                              void* d_out, int out_size, void* d_ws, size_t ws_size,
                              hipStream_t stream)
{
  (void)in_sizes; (void)n_in; (void)out_size; (void)ws_size;
  const float* inputs  = (const float*)d_in[0];
  const float* context = (const float*)d_in[1];
  const float* Wq = (const float*)d_in[2];
  const float* bq = (const float*)d_in[3];
  const float* Wk = (const float*)d_in[4];
  const float* bk = (const float*)d_in[5];
  const float* Wv = (const float*)d_in[6];
  const float* bv = (const float*)d_in[7];
  const float* Wp = (const float*)d_in[8];
  const float* bp = (const float*)d_in[9];
  const float* gamma = (const float*)d_in[10];
  const float* beta  = (const float*)d_in[11];
  float* out = (float*)d_out;

  char* p = (char*)d_ws;
  float* xn_f = (float*)p; p += (size_t)16384 * 256 * 4;
  u16* xn_b   = (u16*)p;   p += (size_t)16384 * 256 * 2;
  u16* ctx_b  = (u16*)p;   p += (size_t)16384 * 256 * 2;
  u16* qbuf   = (u16*)p;   p += (size_t)16384 * 256 * 2;
  u16* kbuf   = (u16*)p;   p += (size_t)16384 * 256 * 2;
  u16* vtbuf  = (u16*)p;   p += (size_t)16384 * 256 * 2;
  u16* wqt = (u16*)p; p += (size_t)256 * 256 * 2;
  u16* wkt = (u16*)p; p += (size_t)256 * 256 * 2;
  u16* wvt = (u16*)p; p += (size_t)256 * 256 * 2;
  u16* wpt = (u16*)p; p += (size_t)256 * 256 * 2;
  float* Lq = (float*)p; p += (size_t)2 * 16384 * 4;   // partial row sums
  u16* o0 = xn_b;   // xn_b dead after gemm_qkv
  u16* o1 = ctx_b;  // ctx_b dead after gemm_qkv

  ln_prep<<<dim3(4096, 2), 256, 0, stream>>>(inputs, context, gamma, beta, xn_f, xn_b, ctx_b);
  wtrans<<<dim3(16, 4), 256, 0, stream>>>(Wq, Wk, Wv, Wp, wqt, wkt, wvt, wpt);
  gemm_qkv<<<dim3(256, 3), 256, 0, stream>>>(xn_b, ctx_b, wqt, wkt, wvt, bq, bk, bv, qbuf, kbuf, vtbuf);
  attn_kernel<<<dim3(512), 512, 0, stream>>>(qbuf, kbuf, vtbuf, o0, o1, Lq);
  gemm_proj<<<dim3(256), 256, 0, stream>>>(o0, o1, Lq, wpt, bp, xn_f, out);
}

// Round 8
// 222.228 us; speedup vs baseline: 2.2682x; 2.2682x over previous
//
#include <hip/hip_runtime.h>

typedef short v8s __attribute__((ext_vector_type(8)));
typedef float v4f __attribute__((ext_vector_type(4)));
using u16 = unsigned short;

// ============================================================================
// TILED LAYOUTS (all bf16). Every hot GLOBAL LOAD is base + lane*16B (1KB,
// fully coalesced) -- confirmed r3: attn 134->94.7us from addressing alone.
// r4: q-tile height = K/V reuse (32-row tiles doubled traffic, cancelled TLP).
// r5: raw-barrier null; XCD affinity cuts FETCH 3.4x but not time.
// r6: 2 waves/SIMD same-block = +8% only -> barrier lockstep means phases SUM.
// r7: key-split VOIDED by launch_bounds(512,4): on this toolchain arg2 acts as
//     blocks/CU -> VGPR cap 64 -> massive scratch spill (FETCH 1.1GB, 4x slow).
//     CALIBRATION: VGPR cap = 2048/(arg2 * blockDim/64). Always check VGPR_Count.
// r8: identical key-split, launch_bounds(512,2) -> cap 128 (r6-proven fit).
//     2 blocks/CU co-resident (16 waves = full pool), independent barriers ->
//     cross-block phase overlap at constant traffic.
//
// TILE16 (activations/out, M x 256): fragment tile = 16 rows x 256 ch.
//   idx(row,ch) = ((row>>4)*8 + (ch>>5))*512 + (((ch>>3)&3)*16 + (row&15))*8 + (ch&7)
// WTILE (weights, 256x256):
//   idx(k,n) = ((n>>4)*8 + (k>>5))*512 + (((k>>3)&3)*16 + (n&15))*8 + (k&7)
// VTILE (V^T, per batch): tile(chunk64, chblk, ks32) as B-operand of PV.
//
// QSCALE = log2(e)/16 folded into Wq/bq so attn does exp2f(sc) directly.
// ============================================================================
#define QSCALE 0.09016844f

__device__ __forceinline__ u16 f2b(float f) {
  union { float f; unsigned u; } v; v.f = f;
  unsigned r = v.u + 0x7FFFu + ((v.u >> 16) & 1u);
  return (u16)(r >> 16);
}
__device__ __forceinline__ float b2f(u16 h) {
  union { unsigned u; float f; } v; v.u = ((unsigned)h) << 16;
  return v.f;
}

// ---------------- LayerNorm + bf16 casts (tiled outputs) ----------------
__global__ void ln_prep(const float* __restrict__ x, const float* __restrict__ ctx,
                        const float* __restrict__ gamma, const float* __restrict__ beta,
                        float* __restrict__ xn_f, u16* __restrict__ xn_b,
                        u16* __restrict__ ctx_b)
{
  const int tid = threadIdx.x;
  const int wid = tid >> 6, lane = tid & 63;
  const int row = blockIdx.x * 4 + wid;
  const size_t tidx = ((size_t)(row >> 4) * 8 + (lane >> 3)) * 512 +
                      (((lane >> 1) & 3) * 16 + (row & 15)) * 8 + (lane & 1) * 4;
  if (blockIdx.y == 0) {
    const float4 xv = *(const float4*)(x + (size_t)row * 256 + lane * 4);
    float s1 = xv.x + xv.y + xv.z + xv.w;
    float s2 = xv.x*xv.x + xv.y*xv.y + xv.z*xv.z + xv.w*xv.w;
#pragma unroll
    for (int m = 32; m >= 1; m >>= 1) {
      s1 += __shfl_xor(s1, m);
      s2 += __shfl_xor(s2, m);
    }
    const float mu  = s1 * (1.0f/256.0f);
    const float var = s2 * (1.0f/256.0f) - mu*mu;
    const float rs  = rsqrtf(var + 1e-3f);
    const float4 g = *(const float4*)(gamma + lane*4);
    const float4 b = *(const float4*)(beta  + lane*4);
    float4 y;
    y.x = (xv.x-mu)*rs*g.x + b.x;
    y.y = (xv.y-mu)*rs*g.y + b.y;
    y.z = (xv.z-mu)*rs*g.z + b.z;
    y.w = (xv.w-mu)*rs*g.w + b.w;
    *(float4*)(xn_f + (size_t)row*256 + lane*4) = y;
    ushort4 yb; yb.x=f2b(y.x); yb.y=f2b(y.y); yb.z=f2b(y.z); yb.w=f2b(y.w);
    *(ushort4*)(xn_b + tidx) = yb;
  } else {
    const float4 cv = *(const float4*)(ctx + (size_t)row * 256 + lane * 4);
    ushort4 cb; cb.x=f2b(cv.x); cb.y=f2b(cv.y); cb.z=f2b(cv.z); cb.w=f2b(cv.w);
    *(ushort4*)(ctx_b + tidx) = cb;
  }
}

// ---------------- weight transpose + bf16 cast into WTILE ----------------
__global__ void wtrans(const float* __restrict__ wq, const float* __restrict__ wk,
                       const float* __restrict__ wv, const float* __restrict__ wp,
                       u16* __restrict__ tq, u16* __restrict__ tk,
                       u16* __restrict__ tv, u16* __restrict__ tp)
{
  const float* src; u16* dst; float scl = 1.0f;
  switch (blockIdx.y) {
    case 0:  src = wq; dst = tq; scl = QSCALE; break;
    case 1:  src = wk; dst = tk; break;
    case 2:  src = wv; dst = tv; break;
    default: src = wp; dst = tp; break;
  }
  const int t  = threadIdx.x;
  const int kk = blockIdx.x * 16 + (t >> 4);
  const int n0 = (t & 15) * 16;
  const size_t base = (size_t)((t & 15) * 8 + (kk >> 5)) * 512 +
                      ((kk >> 3) & 3) * 16 * 8 + (kk & 7);
#pragma unroll
  for (int j = 0; j < 16; j++)
    dst[base + (size_t)j * 8] = f2b(src[(size_t)kk * 256 + n0 + j] * scl);
}

// ---------------- q/k/v GEMM (r4 version, proven) ----------------
__global__ __launch_bounds__(256) void gemm_qkv(
    const u16* __restrict__ xn_b, const u16* __restrict__ ctx_b,
    const u16* __restrict__ wqt, const u16* __restrict__ wkt, const u16* __restrict__ wvt,
    const float* __restrict__ bq, const float* __restrict__ bk, const float* __restrict__ bv,
    u16* __restrict__ qo, u16* __restrict__ ko, u16* __restrict__ vto)
{
  const int mode = blockIdx.y;
  const u16* A; const u16* Wt; const float* bias;
  if (mode == 0)      { A = xn_b;  Wt = wqt; bias = bq; }
  else if (mode == 1) { A = ctx_b; Wt = wkt; bias = bk; }
  else                { A = ctx_b; Wt = wvt; bias = bv; }
  const float bscale = (mode == 0) ? QSCALE : 1.0f;
  const int wid = threadIdx.x >> 6, lane = threadIdx.x & 63;
  const int lm = lane & 15, q4 = lane >> 4;
  const int m0 = blockIdx.x * 64 + wid * 16;
  const u16* abase = A + (size_t)(m0 >> 4) * 4096 + lane * 8;
  v8s af[8];
#pragma unroll
  for (int kf = 0; kf < 8; kf++) af[kf] = *(const v8s*)(abase + kf * 512);
#pragma unroll
  for (int ct = 0; ct < 16; ct++) {
    const int c = ct * 16 + lm;
    const u16* wbase = Wt + (size_t)ct * 4096 + lane * 8;
    v8s wf[8];
#pragma unroll
    for (int kf = 0; kf < 8; kf++) wf[kf] = *(const v8s*)(wbase + kf * 512);
    v4f a0 = {0.f,0.f,0.f,0.f}, a1 = a0, a2 = a0, a3 = a0;
    a0 = __builtin_amdgcn_mfma_f32_16x16x32_bf16(af[0], wf[0], a0, 0, 0, 0);
    a1 = __builtin_amdgcn_mfma_f32_16x16x32_bf16(af[2], wf[2], a1, 0, 0, 0);
    a2 = __builtin_amdgcn_mfma_f32_16x16x32_bf16(af[4], wf[4], a2, 0, 0, 0);
    a3 = __builtin_amdgcn_mfma_f32_16x16x32_bf16(af[6], wf[6], a3, 0, 0, 0);
    a0 = __builtin_amdgcn_mfma_f32_16x16x32_bf16(af[1], wf[1], a0, 0, 0, 0);
    a1 = __builtin_amdgcn_mfma_f32_16x16x32_bf16(af[3], wf[3], a1, 0, 0, 0);
    a2 = __builtin_amdgcn_mfma_f32_16x16x32_bf16(af[5], wf[5], a2, 0, 0, 0);
    a3 = __builtin_amdgcn_mfma_f32_16x16x32_bf16(af[7], wf[7], a3, 0, 0, 0);
    const v4f acc = (a0 + a1) + (a2 + a3);
    const float bb = bias[c] * bscale;
    if (mode == 2) {
      const int b = m0 >> 12;
      const int chunk = (m0 & 4095) >> 6;
      const int kic = (m0 & 63) + q4 * 4;
      const int ks = kic >> 5;
      const int q4p = (kic >> 3) & 3;
      const size_t idx = ((size_t)(b * 64 + chunk) * 32 + (c >> 4) * 2 + ks) * 512 +
                         (q4p * 16 + (c & 15)) * 8 + (q4 & 1) * 4;
      ushort4 pk;
      pk.x = f2b(acc[0] + bb); pk.y = f2b(acc[1] + bb);
      pk.z = f2b(acc[2] + bb); pk.w = f2b(acc[3] + bb);
      *(ushort4*)(vto + idx) = pk;
    } else {
      u16* out = (mode == 0) ? qo : ko;
      const size_t base = ((size_t)(m0 >> 4) * 8 + (c >> 5)) * 512 +
                          (((c >> 3) & 3) * 16 + q4 * 4) * 8 + (c & 7);
#pragma unroll
      for (int r = 0; r < 4; r++)
        out[base + (size_t)r * 8] = f2b(acc[r] + bb);
    }
  }
}

// ---------------- flash-style attention, v11: key-split (occupancy-fixed) ---
// = v9 body (8 waves, 64-row Q tile, 128-key chunks, coalesced tiled loads)
// over HALF the keys per block. Grid 512 -> 2 independent blocks/CU with
// independent barriers: phase overlap across blocks at constant total traffic.
// launch_bounds(512,2): VGPR cap 128 (r6-proven, no spill); 16 waves/CU = 2
// blocks co-resident (full 2048-VGPR pool, 74.8KB LDS).
// bid decode: batch = (bid&7)>>1 (XCD affinity), ks = bid&1, qblk = bid>>3.
// Each half normalizes O by its own L and writes bf16 to o0/o1; partial row
// sums go to Lq[ks]. gemm_proj recombines.
__global__ __launch_bounds__(512, 2) void attn_kernel(
    const u16* __restrict__ q, const u16* __restrict__ k,
    const u16* __restrict__ vt, u16* __restrict__ o0, u16* __restrict__ o1,
    float* __restrict__ Lq)
{
  __shared__ u16 P[2][64][136];   // [buf][q][key128 +8 pad] bf16, 34.8 KB
  __shared__ float Lp[8][64];
  __shared__ float Lt[64];
  const int bid  = blockIdx.x;
  const int b    = (bid & 7) >> 1;   // batch -> XCD pair
  const int ks   = bid & 1;          // key half
  const int qblk = bid >> 3;         // [0,64)
  const int tid  = threadIdx.x;
  const int w    = tid >> 6, lane = tid & 63;  // w in [0,8)
  const int lm   = lane & 15, q4 = lane >> 4;
  const int m0   = qblk * 64;
  const u16* qb = q  + (size_t)b * 1048576;
  const u16* kb = k  + (size_t)b * 1048576;
  const u16* vb = vt + (size_t)b * 1048576;
  const int c0 = ks * 16;            // first 128-key chunk of this half

  // Q fragments for 4 q-tiles (coalesced 1KB loads), held all kernel
  v8s qf[4][8];
#pragma unroll
  for (int qt = 0; qt < 4; qt++) {
    const u16* qbase = qb + (size_t)((m0 >> 4) + qt) * 4096 + lane * 8;
#pragma unroll
    for (int kf = 0; kf < 8; kf++) qf[qt][kf] = *(const v8s*)(qbase + kf * 512);
  }

  v4f o[4][2];   // [qt][ct]: this wave's 32 channels
#pragma unroll
  for (int qt = 0; qt < 4; qt++)
#pragma unroll
    for (int ct = 0; ct < 2; ct++) o[qt][ct] = (v4f){0.f, 0.f, 0.f, 0.f};
  float lsum[4] = {0.f, 0.f, 0.f, 0.f};

  // K fragments for first chunk: strip = c0*8 + w
  v8s kfr[8];
  {
    const u16* kbase = kb + (size_t)(c0 * 8 + w) * 4096 + lane * 8;
#pragma unroll
    for (int kf = 0; kf < 8; kf++) kfr[kf] = *(const v8s*)(kbase + kf * 512);
  }

  for (int c128 = c0; c128 < c0 + 16; c128++) {
    const int pb = c128 & 1;
    // V loads for this chunk (this wave's 2 ch-blocks x 4 key-slices)
    v8s vfr[2][4];
#pragma unroll
    for (int ct = 0; ct < 2; ct++)
#pragma unroll
      for (int j = 0; j < 4; j++) {
        const size_t tile = (size_t)(c128 * 2 + (j >> 1)) * 32 +
                            (w * 2 + ct) * 2 + (j & 1);
        vfr[ct][j] = *(const v8s*)(vb + tile * 512 + lane * 8);
      }
    // phase A: S^T strip via mfma(K, Q)
    v4f sc[4];
#pragma unroll
    for (int qt = 0; qt < 4; qt++) sc[qt] = (v4f){0.f, 0.f, 0.f, 0.f};
#pragma unroll
    for (int kf = 0; kf < 8; kf++)
#pragma unroll
      for (int qt = 0; qt < 4; qt++)
        sc[qt] = __builtin_amdgcn_mfma_f32_16x16x32_bf16(kfr[kf], qf[qt][kf], sc[qt], 0, 0, 0);
    // K prefetch for next chunk (wrap within this half)
    {
      const int nc = c0 + ((c128 + 1 - c0) & 15);
      const u16* kbase = kb + (size_t)(nc * 8 + w) * 4096 + lane * 8;
#pragma unroll
      for (int kf = 0; kf < 8; kf++) kfr[kf] = *(const v8s*)(kbase + kf * 512);
    }
    // exp2 (scale pre-folded into q) -> packed bf16 -> one b64 write per q-tile
#pragma unroll
    for (int qt = 0; qt < 4; qt++) {
      const float e0 = exp2f(sc[qt][0]);
      const float e1 = exp2f(sc[qt][1]);
      const float e2 = exp2f(sc[qt][2]);
      const float e3 = exp2f(sc[qt][3]);
      lsum[qt] += (e0 + e1) + (e2 + e3);
      unsigned d0, d1;
      asm("v_cvt_pk_bf16_f32 %0, %1, %2" : "=v"(d0) : "v"(e0), "v"(e1));
      asm("v_cvt_pk_bf16_f32 %0, %1, %2" : "=v"(d1) : "v"(e2), "v"(e3));
      uint2 pk; pk.x = d0; pk.y = d1;
      *(uint2*)(&P[pb][qt * 16 + lm][w * 16 + q4 * 4]) = pk;
    }
    __syncthreads();
    // phase B: O[64q x 32ch(w)] += P * V over 4 key-slices
#pragma unroll
    for (int qt = 0; qt < 4; qt++) {
      v8s pf[4];
#pragma unroll
      for (int j = 0; j < 4; j++)
        pf[j] = *(const v8s*)(&P[pb][qt * 16 + lm][j * 32 + q4 * 8]);
#pragma unroll
      for (int ct = 0; ct < 2; ct++)
#pragma unroll
        for (int j = 0; j < 4; j++)
          o[qt][ct] = __builtin_amdgcn_mfma_f32_16x16x32_bf16(pf[j], vfr[ct][j], o[qt][ct], 0, 0, 0);
    }
  }

  // partial l reduce: across q4 groups, then across the 8 waves
#pragma unroll
  for (int qt = 0; qt < 4; qt++) {
    float t = lsum[qt];
    t += __shfl_xor(t, 16);
    t += __shfl_xor(t, 32);
    lsum[qt] = t;
  }
  if (q4 == 0) {
#pragma unroll
    for (int qt = 0; qt < 4; qt++) Lp[w][qt * 16 + lm] = lsum[qt];
  }
  __syncthreads();
  if (tid < 64) {
    float t = 0.f;
#pragma unroll
    for (int ww = 0; ww < 8; ww++) t += Lp[ww][tid];
    Lt[tid] = t;
    Lq[ks * 16384 + b * 4096 + m0 + tid] = t;   // partial row-sum for combine
  }
  __syncthreads();

  // own-normalized partial O -> o0/o1 (TILE16 bf16)
  u16* od = ks ? o1 : o0;
  const int rstrip0 = (b * 4096 + m0) >> 4;
#pragma unroll
  for (int qt = 0; qt < 4; qt++)
#pragma unroll
    for (int r = 0; r < 4; r++) {
      const float linv = 1.0f / Lt[qt * 16 + q4 * 4 + r];
#pragma unroll
      for (int ct = 0; ct < 2; ct++) {
        const int ch = w * 32 + ct * 16 + lm;
        const size_t idx = ((size_t)(rstrip0 + qt) * 8 + (ch >> 5)) * 512 +
                           (((ch >> 3) & 3) * 16 + q4 * 4 + r) * 8 + (ch & 7);
        od[idx] = f2b(o[qt][ct][r] * linv);
      }
    }
}

// ---------------- proj GEMM + key-half combine + bias + residual ------------
// A = (L0*o0 + L1*o1)/(L0+L1) per row, rebuilt in registers during A-frag load.
__global__ __launch_bounds__(256) void gemm_proj(
    const u16* __restrict__ o0, const u16* __restrict__ o1,
    const float* __restrict__ Lq,
    const u16* __restrict__ Wt, const float* __restrict__ bias,
    const float* __restrict__ xn_f, float* __restrict__ out)
{
  const int wid = threadIdx.x >> 6, lane = threadIdx.x & 63;
  const int lm = lane & 15, q4 = lane >> 4;
  const int m0 = blockIdx.x * 64 + wid * 16;
  // per-lane row weights (row = m0 + lm for A-fragments)
  const float l0 = Lq[m0 + lm];
  const float l1 = Lq[16384 + m0 + lm];
  const float w0 = l0 / (l0 + l1);
  const float w1 = 1.0f - w0;
  const u16* a0base = o0 + (size_t)(m0 >> 4) * 4096 + lane * 8;
  const u16* a1base = o1 + (size_t)(m0 >> 4) * 4096 + lane * 8;
  v8s af[8];
#pragma unroll
  for (int kf = 0; kf < 8; kf++) {
    const v8s x0 = *(const v8s*)(a0base + kf * 512);
    const v8s x1 = *(const v8s*)(a1base + kf * 512);
    v8s m;
#pragma unroll
    for (int e = 0; e < 8; e++) {
      const float f = w0 * b2f((u16)x0[e]) + w1 * b2f((u16)x1[e]);
      m[e] = (short)f2b(f);
    }
    af[kf] = m;
  }
#pragma unroll
  for (int ct = 0; ct < 16; ct++) {
    const int c = ct * 16 + lm;
    const u16* wbase = Wt + (size_t)ct * 4096 + lane * 8;
    v8s wf[8];
#pragma unroll
    for (int kf = 0; kf < 8; kf++) wf[kf] = *(const v8s*)(wbase + kf * 512);
    v4f a0 = {0.f,0.f,0.f,0.f}, a1 = a0, a2 = a0, a3 = a0;
    a0 = __builtin_amdgcn_mfma_f32_16x16x32_bf16(af[0], wf[0], a0, 0, 0, 0);
    a1 = __builtin_amdgcn_mfma_f32_16x16x32_bf16(af[2], wf[2], a1, 0, 0, 0);
    a2 = __builtin_amdgcn_mfma_f32_16x16x32_bf16(af[4], wf[4], a2, 0, 0, 0);
    a3 = __builtin_amdgcn_mfma_f32_16x16x32_bf16(af[6], wf[6], a3, 0, 0, 0);
    a0 = __builtin_amdgcn_mfma_f32_16x16x32_bf16(af[1], wf[1], a0, 0, 0, 0);
    a1 = __builtin_amdgcn_mfma_f32_16x16x32_bf16(af[3], wf[3], a1, 0, 0, 0);
    a2 = __builtin_amdgcn_mfma_f32_16x16x32_bf16(af[5], wf[5], a2, 0, 0, 0);
    a3 = __builtin_amdgcn_mfma_f32_16x16x32_bf16(af[7], wf[7], a3, 0, 0, 0);
    const v4f acc = (a0 + a1) + (a2 + a3);
    const float bb = bias[c];
#pragma unroll
    for (int r = 0; r < 4; r++) {
      const size_t idx = (size_t)(m0 + q4 * 4 + r) * 256 + c;
      out[idx] = xn_f[idx] + acc[r] + bb;
    }
  }
}

extern "C" void kernel_launch(void* const* d_in, const int* in_sizes, int n_in,
                              void* d_out, int out_size, void* d_ws, size_t ws_size,
                              hipStream_t stream)
{
  (void)in_sizes; (void)n_in; (void)out_size; (void)ws_size;
  const float* inputs  = (const float*)d_in[0];
  const float* context = (const float*)d_in[1];
  const float* Wq = (const float*)d_in[2];
  const float* bq = (const float*)d_in[3];
  const float* Wk = (const float*)d_in[4];
  const float* bk = (const float*)d_in[5];
  const float* Wv = (const float*)d_in[6];
  const float* bv = (const float*)d_in[7];
  const float* Wp = (const float*)d_in[8];
  const float* bp = (const float*)d_in[9];
  const float* gamma = (const float*)d_in[10];
  const float* beta  = (const float*)d_in[11];
  float* out = (float*)d_out;

  char* p = (char*)d_ws;
  float* xn_f = (float*)p; p += (size_t)16384 * 256 * 4;
  u16* xn_b   = (u16*)p;   p += (size_t)16384 * 256 * 2;
  u16* ctx_b  = (u16*)p;   p += (size_t)16384 * 256 * 2;
  u16* qbuf   = (u16*)p;   p += (size_t)16384 * 256 * 2;
  u16* kbuf   = (u16*)p;   p += (size_t)16384 * 256 * 2;
  u16* vtbuf  = (u16*)p;   p += (size_t)16384 * 256 * 2;
  u16* wqt = (u16*)p; p += (size_t)256 * 256 * 2;
  u16* wkt = (u16*)p; p += (size_t)256 * 256 * 2;
  u16* wvt = (u16*)p; p += (size_t)256 * 256 * 2;
  u16* wpt = (u16*)p; p += (size_t)256 * 256 * 2;
  float* Lq = (float*)p; p += (size_t)2 * 16384 * 4;   // partial row sums
  u16* o0 = xn_b;   // xn_b dead after gemm_qkv
  u16* o1 = ctx_b;  // ctx_b dead after gemm_qkv

  ln_prep<<<dim3(4096, 2), 256, 0, stream>>>(inputs, context, gamma, beta, xn_f, xn_b, ctx_b);
  wtrans<<<dim3(16, 4), 256, 0, stream>>>(Wq, Wk, Wv, Wp, wqt, wkt, wvt, wpt);
  gemm_qkv<<<dim3(256, 3), 256, 0, stream>>>(xn_b, ctx_b, wqt, wkt, wvt, bq, bk, bv, qbuf, kbuf, vtbuf);
  attn_kernel<<<dim3(512), 512, 0, stream>>>(qbuf, kbuf, vtbuf, o0, o1, Lq);
  gemm_proj<<<dim3(256), 256, 0, stream>>>(o0, o1, Lq, wpt, bp, xn_f, out);
}

// Round 9
// 212.720 us; speedup vs baseline: 2.3696x; 1.0447x over previous
//
#include <hip/hip_runtime.h>

typedef short v8s __attribute__((ext_vector_type(8)));
typedef float v4f __attribute__((ext_vector_type(4)));
using u16 = unsigned short;

// ============================================================================
// TILED LAYOUTS (all bf16). Every hot GLOBAL LOAD is base + lane*16B (1KB,
// fully coalesced) -- confirmed r3: attn 134->94.7us from addressing alone.
// r4: q-tile height = K/V reuse. r5: raw-barrier null; XCD affinity cuts FETCH
// 3.4x but not time. r6: +8 waves same block = +8% (phases SUM under barrier).
// r7: launch_bounds(512,4) -> VGPR 64 -> spill catastrophe (calibration:
//     VGPR cap = 2048/(arg2*blockDim/64); always check VGPR_Count).
// r8: key-split @128 VGPR clean = NULL (93 vs 90.5; occupancy unchanged).
//     ATTN DECLARED STRUCTURAL ~90us. Reverted to r6 version.
// r9: non-attn (126us vs ~35us roofline) attacked via the r3-proven TA-segment
//     mechanism, applied to STORES: every producer kernel now computes into an
//     LDS tile laid out as its (contiguous) destination region, then blasts it
//     with coalesced 16B/lane copies. gemm_proj also coalesces the xn_f read.
//
// TILE16 (activations/out, M x 256): fragment tile = 16 rows x 256 ch.
//   idx(row,ch) = ((row>>4)*8 + (ch>>5))*512 + (((ch>>3)&3)*16 + (row&15))*8 + (ch&7)
//   -> one 16-row strip = 4096 u16 = 8KB CONTIGUOUS.
// WTILE (weights, 256x256):
//   idx(k,n) = ((n>>4)*8 + (k>>5))*512 + (((k>>3)&3)*16 + (n&15))*8 + (k&7)
// VTILE (V^T, per batch): tile(chunk64, chblk, ks32); one 64-key chunk =
//   16384 u16 = 32KB CONTIGUOUS.
//
// QSCALE = log2(e)/16 folded into Wq/bq so attn does exp2f(sc) directly.
// ============================================================================
#define QSCALE 0.09016844f

__device__ __forceinline__ u16 f2b(float f) {
  union { float f; unsigned u; } v; v.f = f;
  unsigned r = v.u + 0x7FFFu + ((v.u >> 16) & 1u);
  return (u16)(r >> 16);
}

// ---------------- LayerNorm + bf16 casts (LDS-bounced tiled stores) ---------
// Block = 16 rows (one TILE16 strip). Phase 1: 4 waves x 4 rows, LN stats via
// 64-lane butterfly, bf16 into LDS. Phase 2: strip = 8KB contiguous -> blast.
__global__ __launch_bounds__(256) void ln_prep(
    const float* __restrict__ x, const float* __restrict__ ctx,
    const float* __restrict__ gamma, const float* __restrict__ beta,
    float* __restrict__ xn_f, u16* __restrict__ xn_b, u16* __restrict__ ctx_b)
{
  __shared__ u16 Y[16][264];   // +8 pad: phase-2 reads stride 528B -> ~2-way
  const int tid = threadIdx.x;
  const int w = tid >> 6, lane = tid & 63;
  const int rowg0 = blockIdx.x * 16;
  if (blockIdx.y == 0) {
    const float4 g = *(const float4*)(gamma + lane*4);
    const float4 b = *(const float4*)(beta  + lane*4);
#pragma unroll
    for (int rr = 0; rr < 4; rr++) {
      const int r16 = w * 4 + rr;
      const int row = rowg0 + r16;
      const float4 xv = *(const float4*)(x + (size_t)row * 256 + lane * 4);
      float s1 = xv.x + xv.y + xv.z + xv.w;
      float s2 = xv.x*xv.x + xv.y*xv.y + xv.z*xv.z + xv.w*xv.w;
#pragma unroll
      for (int m = 32; m >= 1; m >>= 1) {
        s1 += __shfl_xor(s1, m);
        s2 += __shfl_xor(s2, m);
      }
      const float mu  = s1 * (1.0f/256.0f);
      const float var = s2 * (1.0f/256.0f) - mu*mu;
      const float rs  = rsqrtf(var + 1e-3f);
      float4 y;
      y.x = (xv.x-mu)*rs*g.x + b.x;
      y.y = (xv.y-mu)*rs*g.y + b.y;
      y.z = (xv.z-mu)*rs*g.z + b.z;
      y.w = (xv.w-mu)*rs*g.w + b.w;
      *(float4*)(xn_f + (size_t)row*256 + lane*4) = y;   // row-major, coalesced
      ushort4 yb; yb.x=f2b(y.x); yb.y=f2b(y.y); yb.z=f2b(y.z); yb.w=f2b(y.w);
      *(ushort4*)(&Y[r16][lane*4]) = yb;
    }
  } else {
#pragma unroll
    for (int rr = 0; rr < 4; rr++) {
      const int r16 = w * 4 + rr;
      const int row = rowg0 + r16;
      const float4 cv = *(const float4*)(ctx + (size_t)row * 256 + lane * 4);
      ushort4 cb; cb.x=f2b(cv.x); cb.y=f2b(cv.y); cb.z=f2b(cv.z); cb.w=f2b(cv.w);
      *(ushort4*)(&Y[r16][lane*4]) = cb;
    }
  }
  __syncthreads();
  // blast: 8KB strip contiguous, 256 thr x 2 x 16B
  u16* dst = (blockIdx.y == 0 ? xn_b : ctx_b) + (size_t)blockIdx.x * 4096;
#pragma unroll
  for (int j = 0; j < 2; j++) {
    const int o8  = tid + j * 256;        // 16B-unit index in strip
    const int sub = o8 >> 6, within = o8 & 63;
    const int row = within & 15, chq = within >> 4;
    const int ch  = sub * 32 + chq * 8;
    *(v8s*)(dst + (size_t)o8 * 8) = *(const v8s*)(&Y[row][ch]);
  }
}

// ---------------- weight transpose + bf16 cast into WTILE ----------------
__global__ void wtrans(const float* __restrict__ wq, const float* __restrict__ wk,
                       const float* __restrict__ wv, const float* __restrict__ wp,
                       u16* __restrict__ tq, u16* __restrict__ tk,
                       u16* __restrict__ tv, u16* __restrict__ tp)
{
  const float* src; u16* dst; float scl = 1.0f;
  switch (blockIdx.y) {
    case 0:  src = wq; dst = tq; scl = QSCALE; break;
    case 1:  src = wk; dst = tk; break;
    case 2:  src = wv; dst = tv; break;
    default: src = wp; dst = tp; break;
  }
  const int t  = threadIdx.x;
  const int kk = blockIdx.x * 16 + (t >> 4);
  const int n0 = (t & 15) * 16;
  const size_t base = (size_t)((t & 15) * 8 + (kk >> 5)) * 512 +
                      ((kk >> 3) & 3) * 16 * 8 + (kk & 7);
#pragma unroll
  for (int j = 0; j < 16; j++)
    dst[base + (size_t)j * 8] = f2b(src[(size_t)kk * 256 + n0 + j] * scl);
}

// ---------------- q/k/v GEMM (LDS-bounced stores) ----------------
// r4 compute (64 rows/block, 4 waves, ILP-4 chains) but results land in a
// 32KB LDS tile in the EXACT destination layout, then one coalesced blast.
__global__ __launch_bounds__(256) void gemm_qkv(
    const u16* __restrict__ xn_b, const u16* __restrict__ ctx_b,
    const u16* __restrict__ wqt, const u16* __restrict__ wkt, const u16* __restrict__ wvt,
    const float* __restrict__ bq, const float* __restrict__ bk, const float* __restrict__ bv,
    u16* __restrict__ qo, u16* __restrict__ ko, u16* __restrict__ vto)
{
  __shared__ u16 Cb[16384];   // 32 KB: block's output region, final layout
  const int mode = blockIdx.y;
  const u16* A; const u16* Wt; const float* bias;
  if (mode == 0)      { A = xn_b;  Wt = wqt; bias = bq; }
  else if (mode == 1) { A = ctx_b; Wt = wkt; bias = bk; }
  else                { A = ctx_b; Wt = wvt; bias = bv; }
  const float bscale = (mode == 0) ? QSCALE : 1.0f;
  const int wid = threadIdx.x >> 6, lane = threadIdx.x & 63;
  const int lm = lane & 15, q4 = lane >> 4;
  const int m0b = blockIdx.x * 64;
  const int m0 = m0b + wid * 16;
  const u16* abase = A + (size_t)(m0 >> 4) * 4096 + lane * 8;
  v8s af[8];
#pragma unroll
  for (int kf = 0; kf < 8; kf++) af[kf] = *(const v8s*)(abase + kf * 512);
#pragma unroll
  for (int ct = 0; ct < 16; ct++) {
    const int c = ct * 16 + lm;
    const u16* wbase = Wt + (size_t)ct * 4096 + lane * 8;
    v8s wf[8];
#pragma unroll
    for (int kf = 0; kf < 8; kf++) wf[kf] = *(const v8s*)(wbase + kf * 512);
    v4f a0 = {0.f,0.f,0.f,0.f}, a1 = a0, a2 = a0, a3 = a0;
    a0 = __builtin_amdgcn_mfma_f32_16x16x32_bf16(af[0], wf[0], a0, 0, 0, 0);
    a1 = __builtin_amdgcn_mfma_f32_16x16x32_bf16(af[2], wf[2], a1, 0, 0, 0);
    a2 = __builtin_amdgcn_mfma_f32_16x16x32_bf16(af[4], wf[4], a2, 0, 0, 0);
    a3 = __builtin_amdgcn_mfma_f32_16x16x32_bf16(af[6], wf[6], a3, 0, 0, 0);
    a0 = __builtin_amdgcn_mfma_f32_16x16x32_bf16(af[1], wf[1], a0, 0, 0, 0);
    a1 = __builtin_amdgcn_mfma_f32_16x16x32_bf16(af[3], wf[3], a1, 0, 0, 0);
    a2 = __builtin_amdgcn_mfma_f32_16x16x32_bf16(af[5], wf[5], a2, 0, 0, 0);
    a3 = __builtin_amdgcn_mfma_f32_16x16x32_bf16(af[7], wf[7], a3, 0, 0, 0);
    const v4f acc = (a0 + a1) + (a2 + a3);
    const float bb = bias[c] * bscale;
    if (mode == 2) {
      // VTILE local coords within this block's 32KB chunk region
      const int kic = (m0 & 63) + q4 * 4;     // = wid*16 + q4*4
      const int ks  = kic >> 5;
      const int q4p = (kic >> 3) & 3;
      const int lidx = ((c >> 4) * 2 + ks) * 512 + (q4p * 16 + (c & 15)) * 8 + (q4 & 1) * 4;
      ushort4 pk;
      pk.x = f2b(acc[0] + bb); pk.y = f2b(acc[1] + bb);
      pk.z = f2b(acc[2] + bb); pk.w = f2b(acc[3] + bb);
      *(ushort4*)(&Cb[lidx]) = pk;
    } else {
      // TILE16 local coords within this block's 4 strips (32KB)
      const int lidx = wid * 4096 + (c >> 5) * 512 +
                       (((c >> 3) & 3) * 16 + q4 * 4) * 8 + (c & 7);
#pragma unroll
      for (int r = 0; r < 4; r++) Cb[lidx + r * 8] = f2b(acc[r] + bb);
    }
  }
  __syncthreads();
  // blast: 32KB contiguous, 256 thr x 8 x 16B
  u16* gdst;
  if (mode == 2) {
    const int b = m0b >> 12, chunk = (m0b & 4095) >> 6;
    gdst = vto + (size_t)(b * 64 + chunk) * 16384;
  } else {
    gdst = (mode == 0 ? qo : ko) + (size_t)(m0b >> 4) * 4096;
  }
#pragma unroll
  for (int j = 0; j < 8; j++) {
    const int o8 = threadIdx.x + j * 256;
    *(v8s*)(gdst + (size_t)o8 * 8) = *(const v8s*)(&Cb[o8 * 8]);
  }
}

// ---------------- flash-style attention (r6 version, structural ~90us) ------
__global__ __launch_bounds__(512, 2) void attn_kernel(
    const u16* __restrict__ q, const u16* __restrict__ k,
    const u16* __restrict__ vt, u16* __restrict__ ao)
{
  __shared__ u16 P[2][64][136];   // [buf][q][key128 +8 pad] bf16, 34.8 KB
  __shared__ float Lp[8][64];
  __shared__ float Lt[64];
  const int bid  = blockIdx.x;
  const int b    = (bid & 7) >> 1;                 // batch -> XCD pair
  const int qblk = ((bid >> 3) << 1) | (bid & 1);  // [0,64)
  const int tid  = threadIdx.x;
  const int w    = tid >> 6, lane = tid & 63;      // w in [0,8)
  const int lm   = lane & 15, q4 = lane >> 4;
  const int m0   = qblk * 64;
  const u16* qb = q  + (size_t)b * 1048576;
  const u16* kb = k  + (size_t)b * 1048576;
  const u16* vb = vt + (size_t)b * 1048576;

  v8s qf[4][8];
#pragma unroll
  for (int qt = 0; qt < 4; qt++) {
    const u16* qbase = qb + (size_t)((m0 >> 4) + qt) * 4096 + lane * 8;
#pragma unroll
    for (int kf = 0; kf < 8; kf++) qf[qt][kf] = *(const v8s*)(qbase + kf * 512);
  }

  v4f o[4][2];
#pragma unroll
  for (int qt = 0; qt < 4; qt++)
#pragma unroll
    for (int ct = 0; ct < 2; ct++) o[qt][ct] = (v4f){0.f, 0.f, 0.f, 0.f};
  float lsum[4] = {0.f, 0.f, 0.f, 0.f};

  v8s kfr[8];
  {
    const u16* kbase = kb + (size_t)w * 4096 + lane * 8;
#pragma unroll
    for (int kf = 0; kf < 8; kf++) kfr[kf] = *(const v8s*)(kbase + kf * 512);
  }

  for (int c128 = 0; c128 < 32; c128++) {
    const int pb = c128 & 1;
    v8s vfr[2][4];
#pragma unroll
    for (int ct = 0; ct < 2; ct++)
#pragma unroll
      for (int j = 0; j < 4; j++) {
        const size_t tile = (size_t)(c128 * 2 + (j >> 1)) * 32 +
                            (w * 2 + ct) * 2 + (j & 1);
        vfr[ct][j] = *(const v8s*)(vb + tile * 512 + lane * 8);
      }
    v4f sc[4];
#pragma unroll
    for (int qt = 0; qt < 4; qt++) sc[qt] = (v4f){0.f, 0.f, 0.f, 0.f};
#pragma unroll
    for (int kf = 0; kf < 8; kf++)
#pragma unroll
      for (int qt = 0; qt < 4; qt++)
        sc[qt] = __builtin_amdgcn_mfma_f32_16x16x32_bf16(kfr[kf], qf[qt][kf], sc[qt], 0, 0, 0);
    {
      const int nc = (c128 + 1) & 31;
      const u16* kbase = kb + (size_t)(nc * 8 + w) * 4096 + lane * 8;
#pragma unroll
      for (int kf = 0; kf < 8; kf++) kfr[kf] = *(const v8s*)(kbase + kf * 512);
    }
#pragma unroll
    for (int qt = 0; qt < 4; qt++) {
      const float e0 = exp2f(sc[qt][0]);
      const float e1 = exp2f(sc[qt][1]);
      const float e2 = exp2f(sc[qt][2]);
      const float e3 = exp2f(sc[qt][3]);
      lsum[qt] += (e0 + e1) + (e2 + e3);
      unsigned d0, d1;
      asm("v_cvt_pk_bf16_f32 %0, %1, %2" : "=v"(d0) : "v"(e0), "v"(e1));
      asm("v_cvt_pk_bf16_f32 %0, %1, %2" : "=v"(d1) : "v"(e2), "v"(e3));
      uint2 pk; pk.x = d0; pk.y = d1;
      *(uint2*)(&P[pb][qt * 16 + lm][w * 16 + q4 * 4]) = pk;
    }
    __syncthreads();
#pragma unroll
    for (int qt = 0; qt < 4; qt++) {
      v8s pf[4];
#pragma unroll
      for (int j = 0; j < 4; j++)
        pf[j] = *(const v8s*)(&P[pb][qt * 16 + lm][j * 32 + q4 * 8]);
#pragma unroll
      for (int ct = 0; ct < 2; ct++)
#pragma unroll
        for (int j = 0; j < 4; j++)
          o[qt][ct] = __builtin_amdgcn_mfma_f32_16x16x32_bf16(pf[j], vfr[ct][j], o[qt][ct], 0, 0, 0);
    }
  }

#pragma unroll
  for (int qt = 0; qt < 4; qt++) {
    float t = lsum[qt];
    t += __shfl_xor(t, 16);
    t += __shfl_xor(t, 32);
    lsum[qt] = t;
  }
  if (q4 == 0) {
#pragma unroll
    for (int qt = 0; qt < 4; qt++) Lp[w][qt * 16 + lm] = lsum[qt];
  }
  __syncthreads();
  if (tid < 64) {
    float t = 0.f;
#pragma unroll
    for (int ww = 0; ww < 8; ww++) t += Lp[ww][tid];
    Lt[tid] = t;
  }
  __syncthreads();

  const int rstrip0 = (b * 4096 + m0) >> 4;
#pragma unroll
  for (int qt = 0; qt < 4; qt++)
#pragma unroll
    for (int r = 0; r < 4; r++) {
      const float linv = 1.0f / Lt[qt * 16 + q4 * 4 + r];
#pragma unroll
      for (int ct = 0; ct < 2; ct++) {
        const int ch = w * 32 + ct * 16 + lm;
        const size_t idx = ((size_t)(rstrip0 + qt) * 8 + (ch >> 5)) * 512 +
                           (((ch >> 3) & 3) * 16 + q4 * 4 + r) * 8 + (ch & 7);
        ao[idx] = f2b(o[qt][ct][r] * linv);
      }
    }
}

// ---------------- proj GEMM + bias + residual (LDS-bounced I/O) -------------
// Block's output = 64 rows x 256 f32 = 64KB row-major contiguous. acc+bias go
// to a col-swizzled f32 LDS tile; blast phase reads xn_f COALESCED, adds, and
// stores out COALESCED (fixes both the scattered store AND the scattered
// xn_f read of the previous version).
__global__ __launch_bounds__(256) void gemm_proj(
    const u16* __restrict__ A, const u16* __restrict__ Wt, const float* __restrict__ bias,
    const float* __restrict__ xn_f, float* __restrict__ out)
{
  __shared__ float Cf[64][256];   // 64 KB exactly; col ^= q4*8 (bank spread)
  const int wid = threadIdx.x >> 6, lane = threadIdx.x & 63;
  const int lm = lane & 15, q4 = lane >> 4;
  const int m0b = blockIdx.x * 64;
  const int m0 = m0b + wid * 16;
  const u16* abase = A + (size_t)(m0 >> 4) * 4096 + lane * 8;
  v8s af[8];
#pragma unroll
  for (int kf = 0; kf < 8; kf++) af[kf] = *(const v8s*)(abase + kf * 512);
#pragma unroll
  for (int ct = 0; ct < 16; ct++) {
    const int c = ct * 16 + lm;
    const u16* wbase = Wt + (size_t)ct * 4096 + lane * 8;
    v8s wf[8];
#pragma unroll
    for (int kf = 0; kf < 8; kf++) wf[kf] = *(const v8s*)(wbase + kf * 512);
    v4f a0 = {0.f,0.f,0.f,0.f}, a1 = a0, a2 = a0, a3 = a0;
    a0 = __builtin_amdgcn_mfma_f32_16x16x32_bf16(af[0], wf[0], a0, 0, 0, 0);
    a1 = __builtin_amdgcn_mfma_f32_16x16x32_bf16(af[2], wf[2], a1, 0, 0, 0);
    a2 = __builtin_amdgcn_mfma_f32_16x16x32_bf16(af[4], wf[4], a2, 0, 0, 0);
    a3 = __builtin_amdgcn_mfma_f32_16x16x32_bf16(af[6], wf[6], a3, 0, 0, 0);
    a0 = __builtin_amdgcn_mfma_f32_16x16x32_bf16(af[1], wf[1], a0, 0, 0, 0);
    a1 = __builtin_amdgcn_mfma_f32_16x16x32_bf16(af[3], wf[3], a1, 0, 0, 0);
    a2 = __builtin_amdgcn_mfma_f32_16x16x32_bf16(af[5], wf[5], a2, 0, 0, 0);
    a3 = __builtin_amdgcn_mfma_f32_16x16x32_bf16(af[7], wf[7], a3, 0, 0, 0);
    const v4f acc = (a0 + a1) + (a2 + a3);
    const float bb = bias[c];
#pragma unroll
    for (int r = 0; r < 4; r++) {
      const int row = wid * 16 + q4 * 4 + r;
      Cf[row][c ^ (q4 * 8)] = acc[r] + bb;   // (row>>2)&3 == q4
    }
  }
  __syncthreads();
  const float* xb = xn_f + (size_t)m0b * 256;
  float* ob = out + (size_t)m0b * 256;
#pragma unroll
  for (int j = 0; j < 16; j++) {
    const int u = threadIdx.x + j * 256;   // float4-unit index in 64KB tile
    const int row = u >> 6;
    const int c = (u & 63) * 4;
    const int csw = c ^ (((row >> 2) & 3) * 8);
    const float4 a4 = *(const float4*)(&Cf[row][csw]);
    const float4 x4 = *(const float4*)(xb + (size_t)row * 256 + c);
    float4 o4;
    o4.x = a4.x + x4.x; o4.y = a4.y + x4.y;
    o4.z = a4.z + x4.z; o4.w = a4.w + x4.w;
    *(float4*)(ob + (size_t)row * 256 + c) = o4;
  }
}

extern "C" void kernel_launch(void* const* d_in, const int* in_sizes, int n_in,
                              void* d_out, int out_size, void* d_ws, size_t ws_size,
                              hipStream_t stream)
{
  (void)in_sizes; (void)n_in; (void)out_size; (void)ws_size;
  const float* inputs  = (const float*)d_in[0];
  const float* context = (const float*)d_in[1];
  const float* Wq = (const float*)d_in[2];
  const float* bq = (const float*)d_in[3];
  const float* Wk = (const float*)d_in[4];
  const float* bk = (const float*)d_in[5];
  const float* Wv = (const float*)d_in[6];
  const float* bv = (const float*)d_in[7];
  const float* Wp = (const float*)d_in[8];
  const float* bp = (const float*)d_in[9];
  const float* gamma = (const float*)d_in[10];
  const float* beta  = (const float*)d_in[11];
  float* out = (float*)d_out;

  char* p = (char*)d_ws;
  float* xn_f = (float*)p; p += (size_t)16384 * 256 * 4;
  u16* xn_b   = (u16*)p;   p += (size_t)16384 * 256 * 2;
  u16* ctx_b  = (u16*)p;   p += (size_t)16384 * 256 * 2;
  u16* qbuf   = (u16*)p;   p += (size_t)16384 * 256 * 2;
  u16* kbuf   = (u16*)p;   p += (size_t)16384 * 256 * 2;
  u16* vtbuf  = (u16*)p;   p += (size_t)16384 * 256 * 2;
  u16* wqt = (u16*)p; p += (size_t)256 * 256 * 2;
  u16* wkt = (u16*)p; p += (size_t)256 * 256 * 2;
  u16* wvt = (u16*)p; p += (size_t)256 * 256 * 2;
  u16* wpt = (u16*)p; p += (size_t)256 * 256 * 2;
  u16* aobuf = xn_b;  // xn_b dead after gemm_qkv

  ln_prep<<<dim3(1024, 2), 256, 0, stream>>>(inputs, context, gamma, beta, xn_f, xn_b, ctx_b);
  wtrans<<<dim3(16, 4), 256, 0, stream>>>(Wq, Wk, Wv, Wp, wqt, wkt, wvt, wpt);
  gemm_qkv<<<dim3(256, 3), 256, 0, stream>>>(xn_b, ctx_b, wqt, wkt, wvt, bq, bk, bv, qbuf, kbuf, vtbuf);
  attn_kernel<<<dim3(256), 512, 0, stream>>>(qbuf, kbuf, vtbuf, aobuf);
  gemm_proj<<<dim3(256), 256, 0, stream>>>(aobuf, wpt, bp, xn_f, out);
}

// Round 11
// 209.321 us; speedup vs baseline: 2.4080x; 1.0162x over previous
//
#include <hip/hip_runtime.h>

typedef short v8s __attribute__((ext_vector_type(8)));
typedef float v4f __attribute__((ext_vector_type(4)));
using u16 = unsigned short;

// ============================================================================
// r11 = r10 fusion retry with the LDS overflow fixed.
// r10 FAILED TO RUN: attn LDS union peaked at 67.8KB (OT f32[64][256] 64KB +
// Lp/Lt) > 64KB sharedMemPerBlock -> launch failure. Fix: drop the OT bounce
// (r9 proved store-bouncing is worth ~0) and store the proj epilogue directly
// (old gemm_proj scatter pattern, proven r4-r9). Union now {P|Yt} = 34.8KB,
// total 37.1KB -- identical to the r9-proven footprint.
//
// PIPELINE: 3 kernels. wtrans -> gemm_qkv (LN/cast fused) -> attn(+proj+res).
// Removes ln_prep + gemm_proj stages, xn_b/ctx_b/aobuf round-trips (~75MB),
// two serialization points. attn main loop = r6/r9-proven body, untouched.
// History: r3 coalesced loads 134->94.7; r4 ILP-4 chains (-28us non-attn);
// r5 raw-barrier null; r6 8-wave +8%; r7 launch_bounds calibration
// (VGPR cap = 2048/(arg2*blockDim/64)); r8 key-split null -> attn structural
// ~90us; r9 store-bounce null -> non-attn residual believed stage overhead.
//
// TILE16 (activations, M x 256): idx(row,ch) =
//   ((row>>4)*8 + (ch>>5))*512 + (((ch>>3)&3)*16 + (row&15))*8 + (ch&7)
// WTILE (weights 256x256): idx(k,n) =
//   ((n>>4)*8 + (k>>5))*512 + (((k>>3)&3)*16 + (n&15))*8 + (k&7)
// VTILE (V^T per batch): tile(chunk64, chblk, ks32), 32KB/chunk contiguous.
// QSCALE = log2(e)/16 folded into Wq/bq.
// ============================================================================
#define QSCALE 0.09016844f

__device__ __forceinline__ u16 f2b(float f) {
  union { float f; unsigned u; } v; v.f = f;
  unsigned r = v.u + 0x7FFFu + ((v.u >> 16) & 1u);
  return (u16)(r >> 16);
}

// ---------------- weight transpose + bf16 cast into WTILE ----------------
__global__ void wtrans(const float* __restrict__ wq, const float* __restrict__ wk,
                       const float* __restrict__ wv, const float* __restrict__ wp,
                       u16* __restrict__ tq, u16* __restrict__ tk,
                       u16* __restrict__ tv, u16* __restrict__ tp)
{
  const float* src; u16* dst; float scl = 1.0f;
  switch (blockIdx.y) {
    case 0:  src = wq; dst = tq; scl = QSCALE; break;
    case 1:  src = wk; dst = tk; break;
    case 2:  src = wv; dst = tv; break;
    default: src = wp; dst = tp; break;
  }
  const int t  = threadIdx.x;
  const int kk = blockIdx.x * 16 + (t >> 4);
  const int n0 = (t & 15) * 16;
  const size_t base = (size_t)((t & 15) * 8 + (kk >> 5)) * 512 +
                      ((kk >> 3) & 3) * 16 * 8 + (kk & 7);
#pragma unroll
  for (int j = 0; j < 16; j++)
    dst[base + (size_t)j * 8] = f2b(src[(size_t)kk * 256 + n0 + j] * scl);
}

// ---------------- fused LN/cast + q/k/v GEMM ----------------
// Block = 64 rows, 4 waves, modes via blockIdx.y (0:q from LN(x), 1:k, 2:v
// from ctx). Phase 0: rows -> LDS bf16 tile (mode 0 computes LN + writes
// xn_f). Then MFMA fragments from LDS, r4-proven ct loop, r9-proven LDS-bounce
// store. No global staging of normalized/cast activations.
__global__ __launch_bounds__(256) void gemm_qkv(
    const float* __restrict__ x, const float* __restrict__ ctx,
    const float* __restrict__ gamma, const float* __restrict__ beta,
    const u16* __restrict__ wqt, const u16* __restrict__ wkt, const u16* __restrict__ wvt,
    const float* __restrict__ bq, const float* __restrict__ bk, const float* __restrict__ bv,
    float* __restrict__ xn_f, u16* __restrict__ qo, u16* __restrict__ ko,
    u16* __restrict__ vto)
{
  __shared__ union {
    u16 Y[64][264];   // phase-0 A tile (row-major bf16, +8 pad), 33.8KB
    u16 Cb[16384];    // output bounce (32KB, final layout)
  } S;
  const int mode = blockIdx.y;
  const int wid = threadIdx.x >> 6, lane = threadIdx.x & 63;
  const int lm = lane & 15, q4 = lane >> 4;
  const int m0b = blockIdx.x * 64;

  // phase 0: 16 rows per wave -> LDS
  if (mode == 0) {
    const float4 g = *(const float4*)(gamma + lane * 4);
    const float4 bt = *(const float4*)(beta + lane * 4);
#pragma unroll
    for (int i = 0; i < 16; i++) {
      const int rb = wid * 16 + i;
      const int row = m0b + rb;
      const float4 xv = *(const float4*)(x + (size_t)row * 256 + lane * 4);
      float s1 = xv.x + xv.y + xv.z + xv.w;
      float s2 = xv.x*xv.x + xv.y*xv.y + xv.z*xv.z + xv.w*xv.w;
#pragma unroll
      for (int m = 32; m >= 1; m >>= 1) {
        s1 += __shfl_xor(s1, m);
        s2 += __shfl_xor(s2, m);
      }
      const float mu  = s1 * (1.0f/256.0f);
      const float var = s2 * (1.0f/256.0f) - mu*mu;
      const float rs  = rsqrtf(var + 1e-3f);
      float4 y;
      y.x = (xv.x-mu)*rs*g.x + bt.x;
      y.y = (xv.y-mu)*rs*g.y + bt.y;
      y.z = (xv.z-mu)*rs*g.z + bt.z;
      y.w = (xv.w-mu)*rs*g.w + bt.w;
      *(float4*)(xn_f + (size_t)row * 256 + lane * 4) = y;   // residual copy
      ushort4 yb; yb.x=f2b(y.x); yb.y=f2b(y.y); yb.z=f2b(y.z); yb.w=f2b(y.w);
      *(ushort4*)(&S.Y[rb][lane * 4]) = yb;
    }
  } else {
#pragma unroll
    for (int i = 0; i < 16; i++) {
      const int rb = wid * 16 + i;
      const float4 cv = *(const float4*)(ctx + (size_t)(m0b + rb) * 256 + lane * 4);
      ushort4 cb; cb.x=f2b(cv.x); cb.y=f2b(cv.y); cb.z=f2b(cv.z); cb.w=f2b(cv.w);
      *(ushort4*)(&S.Y[rb][lane * 4]) = cb;
    }
  }
  __syncthreads();

  // A fragments from LDS: lane(q4,lm) -> row wid*16+lm, ch kf*32+q4*8+e
  v8s af[8];
#pragma unroll
  for (int kf = 0; kf < 8; kf++)
    af[kf] = *(const v8s*)(&S.Y[wid * 16 + lm][kf * 32 + q4 * 8]);
  __syncthreads();   // Y dead -> Cb writable

  const u16* Wt; const float* bias;
  if (mode == 0)      { Wt = wqt; bias = bq; }
  else if (mode == 1) { Wt = wkt; bias = bk; }
  else                { Wt = wvt; bias = bv; }
  const float bscale = (mode == 0) ? QSCALE : 1.0f;

#pragma unroll
  for (int ct = 0; ct < 16; ct++) {
    const int c = ct * 16 + lm;
    const u16* wbase = Wt + (size_t)ct * 4096 + lane * 8;
    v8s wf[8];
#pragma unroll
    for (int kf = 0; kf < 8; kf++) wf[kf] = *(const v8s*)(wbase + kf * 512);
    v4f a0 = {0.f,0.f,0.f,0.f}, a1 = a0, a2 = a0, a3 = a0;
    a0 = __builtin_amdgcn_mfma_f32_16x16x32_bf16(af[0], wf[0], a0, 0, 0, 0);
    a1 = __builtin_amdgcn_mfma_f32_16x16x32_bf16(af[2], wf[2], a1, 0, 0, 0);
    a2 = __builtin_amdgcn_mfma_f32_16x16x32_bf16(af[4], wf[4], a2, 0, 0, 0);
    a3 = __builtin_amdgcn_mfma_f32_16x16x32_bf16(af[6], wf[6], a3, 0, 0, 0);
    a0 = __builtin_amdgcn_mfma_f32_16x16x32_bf16(af[1], wf[1], a0, 0, 0, 0);
    a1 = __builtin_amdgcn_mfma_f32_16x16x32_bf16(af[3], wf[3], a1, 0, 0, 0);
    a2 = __builtin_amdgcn_mfma_f32_16x16x32_bf16(af[5], wf[5], a2, 0, 0, 0);
    a3 = __builtin_amdgcn_mfma_f32_16x16x32_bf16(af[7], wf[7], a3, 0, 0, 0);
    const v4f acc = (a0 + a1) + (a2 + a3);
    const float bb = bias[c] * bscale;
    if (mode == 2) {
      const int kic = wid * 16 + q4 * 4;
      const int ks  = kic >> 5;
      const int q4p = (kic >> 3) & 3;
      const int lidx = ((c >> 4) * 2 + ks) * 512 + (q4p * 16 + (c & 15)) * 8 + (q4 & 1) * 4;
      ushort4 pk;
      pk.x = f2b(acc[0] + bb); pk.y = f2b(acc[1] + bb);
      pk.z = f2b(acc[2] + bb); pk.w = f2b(acc[3] + bb);
      *(ushort4*)(&S.Cb[lidx]) = pk;
    } else {
      const int lidx = wid * 4096 + (c >> 5) * 512 +
                       (((c >> 3) & 3) * 16 + q4 * 4) * 8 + (c & 7);
#pragma unroll
      for (int r = 0; r < 4; r++) S.Cb[lidx + r * 8] = f2b(acc[r] + bb);
    }
  }
  __syncthreads();
  // blast: 32KB contiguous
  u16* gdst;
  if (mode == 2) {
    const int b = m0b >> 12, chunk = (m0b & 4095) >> 6;
    gdst = vto + (size_t)(b * 64 + chunk) * 16384;
  } else {
    gdst = (mode == 0 ? qo : ko) + (size_t)(m0b >> 4) * 4096;
  }
#pragma unroll
  for (int j = 0; j < 8; j++) {
    const int o8 = threadIdx.x + j * 256;
    *(v8s*)(gdst + (size_t)o8 * 8) = *(const v8s*)(&S.Cb[o8 * 8]);
  }
}

// ---------------- attention + fused projection + residual ----------------
// Main loop = r6/r9-proven body (89.4us). Epilogue: normalized O -> LDS
// A-tile (aliases dead P) -> per-wave proj GEMM (wave w: strip w>>1, ct half
// w&1) -> bias -> DIRECT store with xn_f residual (old gemm_proj pattern;
// r9 proved bouncing this is worth ~0, and it keeps LDS under 64KB).
__global__ __launch_bounds__(512, 2) void attn_kernel(
    const u16* __restrict__ q, const u16* __restrict__ k,
    const u16* __restrict__ vt, const u16* __restrict__ wpt,
    const float* __restrict__ bp, const float* __restrict__ xn_f,
    float* __restrict__ out)
{
  __shared__ union {
    u16 P[2][64][136];   // main-loop P (34.8KB)
    u16 Yt[64][264];     // epilogue A tile (33.8KB)
  } S;                   // + Lp/Lt: 37.1KB total (= r9-proven footprint)
  __shared__ float Lp[8][64];
  __shared__ float Lt[64];
  const int bid  = blockIdx.x;
  const int b    = (bid & 7) >> 1;                 // batch -> XCD pair
  const int qblk = ((bid >> 3) << 1) | (bid & 1);  // [0,64)
  const int tid  = threadIdx.x;
  const int w    = tid >> 6, lane = tid & 63;      // w in [0,8)
  const int lm   = lane & 15, q4 = lane >> 4;
  const int m0   = qblk * 64;
  const u16* qb = q  + (size_t)b * 1048576;
  const u16* kb = k  + (size_t)b * 1048576;
  const u16* vb = vt + (size_t)b * 1048576;

  v8s qf[4][8];
#pragma unroll
  for (int qt = 0; qt < 4; qt++) {
    const u16* qbase = qb + (size_t)((m0 >> 4) + qt) * 4096 + lane * 8;
#pragma unroll
    for (int kf = 0; kf < 8; kf++) qf[qt][kf] = *(const v8s*)(qbase + kf * 512);
  }

  v4f o[4][2];
#pragma unroll
  for (int qt = 0; qt < 4; qt++)
#pragma unroll
    for (int ct = 0; ct < 2; ct++) o[qt][ct] = (v4f){0.f, 0.f, 0.f, 0.f};
  float lsum[4] = {0.f, 0.f, 0.f, 0.f};

  v8s kfr[8];
  {
    const u16* kbase = kb + (size_t)w * 4096 + lane * 8;
#pragma unroll
    for (int kf = 0; kf < 8; kf++) kfr[kf] = *(const v8s*)(kbase + kf * 512);
  }

  for (int c128 = 0; c128 < 32; c128++) {
    const int pb = c128 & 1;
    v8s vfr[2][4];
#pragma unroll
    for (int ct = 0; ct < 2; ct++)
#pragma unroll
      for (int j = 0; j < 4; j++) {
        const size_t tile = (size_t)(c128 * 2 + (j >> 1)) * 32 +
                            (w * 2 + ct) * 2 + (j & 1);
        vfr[ct][j] = *(const v8s*)(vb + tile * 512 + lane * 8);
      }
    v4f sc[4];
#pragma unroll
    for (int qt = 0; qt < 4; qt++) sc[qt] = (v4f){0.f, 0.f, 0.f, 0.f};
#pragma unroll
    for (int kf = 0; kf < 8; kf++)
#pragma unroll
      for (int qt = 0; qt < 4; qt++)
        sc[qt] = __builtin_amdgcn_mfma_f32_16x16x32_bf16(kfr[kf], qf[qt][kf], sc[qt], 0, 0, 0);
    {
      const int nc = (c128 + 1) & 31;
      const u16* kbase = kb + (size_t)(nc * 8 + w) * 4096 + lane * 8;
#pragma unroll
      for (int kf = 0; kf < 8; kf++) kfr[kf] = *(const v8s*)(kbase + kf * 512);
    }
#pragma unroll
    for (int qt = 0; qt < 4; qt++) {
      const float e0 = exp2f(sc[qt][0]);
      const float e1 = exp2f(sc[qt][1]);
      const float e2 = exp2f(sc[qt][2]);
      const float e3 = exp2f(sc[qt][3]);
      lsum[qt] += (e0 + e1) + (e2 + e3);
      unsigned d0, d1;
      asm("v_cvt_pk_bf16_f32 %0, %1, %2" : "=v"(d0) : "v"(e0), "v"(e1));
      asm("v_cvt_pk_bf16_f32 %0, %1, %2" : "=v"(d1) : "v"(e2), "v"(e3));
      uint2 pk; pk.x = d0; pk.y = d1;
      *(uint2*)(&S.P[pb][qt * 16 + lm][w * 16 + q4 * 4]) = pk;
    }
    __syncthreads();
#pragma unroll
    for (int qt = 0; qt < 4; qt++) {
      v8s pf[4];
#pragma unroll
      for (int j = 0; j < 4; j++)
        pf[j] = *(const v8s*)(&S.P[pb][qt * 16 + lm][j * 32 + q4 * 8]);
#pragma unroll
      for (int ct = 0; ct < 2; ct++)
#pragma unroll
        for (int j = 0; j < 4; j++)
          o[qt][ct] = __builtin_amdgcn_mfma_f32_16x16x32_bf16(pf[j], vfr[ct][j], o[qt][ct], 0, 0, 0);
    }
  }

#pragma unroll
  for (int qt = 0; qt < 4; qt++) {
    float t = lsum[qt];
    t += __shfl_xor(t, 16);
    t += __shfl_xor(t, 32);
    lsum[qt] = t;
  }
  if (q4 == 0) {
#pragma unroll
    for (int qt = 0; qt < 4; qt++) Lp[w][qt * 16 + lm] = lsum[qt];
  }
  __syncthreads();
  if (tid < 64) {
    float t = 0.f;
#pragma unroll
    for (int ww = 0; ww < 8; ww++) t += Lp[ww][tid];
    Lt[tid] = t;
  }
  __syncthreads();

  // ---- epilogue: normalized O -> Yt (clobbers P; barrier-separated) ----
#pragma unroll
  for (int qt = 0; qt < 4; qt++)
#pragma unroll
    for (int r = 0; r < 4; r++) {
      const float linv = 1.0f / Lt[qt * 16 + q4 * 4 + r];
#pragma unroll
      for (int ct = 0; ct < 2; ct++) {
        const int ch = w * 32 + ct * 16 + lm;
        S.Yt[qt * 16 + q4 * 4 + r][ch] = f2b(o[qt][ct][r] * linv);
      }
    }
  __syncthreads();
  // proj A-fragments: wave w -> strip s = w>>1, ct half h = w&1
  const int s = w >> 1, h = w & 1;
  v8s paf[8];
#pragma unroll
  for (int kf = 0; kf < 8; kf++)
    paf[kf] = *(const v8s*)(&S.Yt[s * 16 + lm][kf * 32 + q4 * 8]);
  // direct proj + bias + residual store (old gemm_proj pattern, proven r4-r9)
  const float* xb = xn_f + (size_t)(b * 4096 + m0) * 256;
  float* ob = out + (size_t)(b * 4096 + m0) * 256;
#pragma unroll
  for (int ctl = 0; ctl < 8; ctl++) {
    const int ct = h * 8 + ctl;
    const int c = ct * 16 + lm;
    const u16* wbase = wpt + (size_t)ct * 4096 + lane * 8;
    v8s wf[8];
#pragma unroll
    for (int kf = 0; kf < 8; kf++) wf[kf] = *(const v8s*)(wbase + kf * 512);
    v4f a0 = {0.f,0.f,0.f,0.f}, a1 = a0, a2 = a0, a3 = a0;
    a0 = __builtin_amdgcn_mfma_f32_16x16x32_bf16(paf[0], wf[0], a0, 0, 0, 0);
    a1 = __builtin_amdgcn_mfma_f32_16x16x32_bf16(paf[2], wf[2], a1, 0, 0, 0);
    a2 = __builtin_amdgcn_mfma_f32_16x16x32_bf16(paf[4], wf[4], a2, 0, 0, 0);
    a3 = __builtin_amdgcn_mfma_f32_16x16x32_bf16(paf[6], wf[6], a3, 0, 0, 0);
    a0 = __builtin_amdgcn_mfma_f32_16x16x32_bf16(paf[1], wf[1], a0, 0, 0, 0);
    a1 = __builtin_amdgcn_mfma_f32_16x16x32_bf16(paf[3], wf[3], a1, 0, 0, 0);
    a2 = __builtin_amdgcn_mfma_f32_16x16x32_bf16(paf[5], wf[5], a2, 0, 0, 0);
    a3 = __builtin_amdgcn_mfma_f32_16x16x32_bf16(paf[7], wf[7], a3, 0, 0, 0);
    const v4f acc = (a0 + a1) + (a2 + a3);
    const float bb = bp[c];
#pragma unroll
    for (int r = 0; r < 4; r++) {
      const size_t idx = (size_t)(s * 16 + q4 * 4 + r) * 256 + c;
      ob[idx] = xb[idx] + acc[r] + bb;
    }
  }
}

extern "C" void kernel_launch(void* const* d_in, const int* in_sizes, int n_in,
                              void* d_out, int out_size, void* d_ws, size_t ws_size,
                              hipStream_t stream)
{
  (void)in_sizes; (void)n_in; (void)out_size; (void)ws_size;
  const float* inputs  = (const float*)d_in[0];
  const float* context = (const float*)d_in[1];
  const float* Wq = (const float*)d_in[2];
  const float* bq = (const float*)d_in[3];
  const float* Wk = (const float*)d_in[4];
  const float* bk = (const float*)d_in[5];
  const float* Wv = (const float*)d_in[6];
  const float* bv = (const float*)d_in[7];
  const float* Wp = (const float*)d_in[8];
  const float* bp = (const float*)d_in[9];
  const float* gamma = (const float*)d_in[10];
  const float* beta  = (const float*)d_in[11];
  float* out = (float*)d_out;

  char* p = (char*)d_ws;
  float* xn_f = (float*)p; p += (size_t)16384 * 256 * 4;
  u16* qbuf   = (u16*)p;   p += (size_t)16384 * 256 * 2;
  u16* kbuf   = (u16*)p;   p += (size_t)16384 * 256 * 2;
  u16* vtbuf  = (u16*)p;   p += (size_t)16384 * 256 * 2;
  u16* wqt = (u16*)p; p += (size_t)256 * 256 * 2;
  u16* wkt = (u16*)p; p += (size_t)256 * 256 * 2;
  u16* wvt = (u16*)p; p += (size_t)256 * 256 * 2;
  u16* wpt = (u16*)p; p += (size_t)256 * 256 * 2;

  wtrans<<<dim3(16, 4), 256, 0, stream>>>(Wq, Wk, Wv, Wp, wqt, wkt, wvt, wpt);
  gemm_qkv<<<dim3(256, 3), 256, 0, stream>>>(inputs, context, gamma, beta,
                                             wqt, wkt, wvt, bq, bk, bv,
                                             xn_f, qbuf, kbuf, vtbuf);
  attn_kernel<<<dim3(256), 512, 0, stream>>>(qbuf, kbuf, vtbuf, wpt, bp, xn_f, out);
}